// Round 7
// baseline (1292.779 us; speedup 1.0000x reference)
//
#include <hip/hip_runtime.h>
#include <hip/hip_fp16.h>

constexpr int IN_FEAT = 256;
constexpr int HID     = 64;
constexpr int OUT     = 32;
constexpr int BSH     = 7;            // bucket shift: 128 nodes / bucket
constexpr int BR      = 1 << BSH;     // 128

typedef _Float16 half8 __attribute__((ext_vector_type(8)));
typedef float    f32x4 __attribute__((ext_vector_type(4)));

// ---------------------------------------------------------------------------
// Fold the two linears: wlin[c][k] = sum_h fc1_w[h][k]*gcn_w[h][c]  (f16),
// bhw = fc1_b @ gcn_w. wlin is [32][256] f16 linear = 16KB, L1/L2-resident.
// ---------------------------------------------------------------------------
__global__ __launch_bounds__(256) void prep_W(
    const float* __restrict__ fc1_w,   // [HID][IN_FEAT]
    const float* __restrict__ fc1_b,   // [HID]
    const float* __restrict__ gcn_w,   // [HID][OUT]
    _Float16* __restrict__ wlin,       // [32*256] f16
    float* __restrict__ bhw)           // [OUT]
{
    int idx = blockIdx.x * 256 + threadIdx.x;   // 0 .. 8191
    int k = idx >> 5;
    int c = idx & 31;
    float acc = 0.f;
#pragma unroll
    for (int h = 0; h < HID; ++h)
        acc += fc1_w[h * IN_FEAT + k] * gcn_w[h * OUT + c];
    wlin[c * 256 + k] = (_Float16)acc;

    if (idx < OUT) {
        float b = 0.f;
#pragma unroll
        for (int h = 0; h < HID; ++h)
            b += fc1_b[h] * gcn_w[h * OUT + idx];
        bhw[idx] = b;
    }
}

// ---------------------------------------------------------------------------
// Bucket pipeline: count -> scan -> bin -> per-bucket degree/dinv.
// ---------------------------------------------------------------------------
__global__ __launch_bounds__(256) void zero_i32(int* __restrict__ p, int n)
{
    int i = blockIdx.x * 256 + threadIdx.x;
    if (i < n) p[i] = 0;
}

__global__ __launch_bounds__(256) void bucket_count(
    const int* __restrict__ dst, int* __restrict__ bcnt, int E)
{
    int e = blockIdx.x * 256 + threadIdx.x;
    if (e < E) atomicAdd(&bcnt[dst[e] >> BSH], 1);
}

// single-block parallel exclusive scan of bcnt[NB] -> off[NB+1], cur[NB]
// (NB <= 1024)
__global__ __launch_bounds__(256) void bucket_scan(
    const int* __restrict__ bcnt, int* __restrict__ off, int* __restrict__ cur,
    int NB)
{
    int t = threadIdx.x;
    int i = t * 4;
    int c0 = (i     < NB) ? bcnt[i]     : 0;
    int c1 = (i + 1 < NB) ? bcnt[i + 1] : 0;
    int c2 = (i + 2 < NB) ? bcnt[i + 2] : 0;
    int c3 = (i + 3 < NB) ? bcnt[i + 3] : 0;
    int s = c0 + c1 + c2 + c3;
    int lane = t & 63;
    int incl = s;
    for (int d = 1; d < 64; d <<= 1) {
        int u = __shfl_up(incl, d, 64);
        if (lane >= d) incl += u;
    }
    __shared__ int wtot[4];
    if (lane == 63) wtot[t >> 6] = incl;
    __syncthreads();
    int w = t >> 6;
    int wbase = 0;
    for (int j = 0; j < 4; ++j) if (j < w) wbase += wtot[j];
    int e0 = wbase + incl - s;

    if (i     < NB) { off[i]     = e0;                cur[i]     = e0; }
    if (i + 1 < NB) { off[i + 1] = e0 + c0;           cur[i + 1] = e0 + c0; }
    if (i + 2 < NB) { off[i + 2] = e0 + c0 + c1;      cur[i + 2] = e0 + c0 + c1; }
    if (i + 3 < NB) { off[i + 3] = e0 + c0 + c1 + c2; cur[i + 3] = e0 + c0 + c1 + c2; }
    if (t == 0) off[NB] = wtot[0] + wtot[1] + wtot[2] + wtot[3];
}

// bin edges into dst-bucket regions as {src, dst} records
__global__ __launch_bounds__(256) void bin_edges(
    const int* __restrict__ src, const int* __restrict__ dst,
    int* __restrict__ cur, int2* __restrict__ edata, int E)
{
    int e = blockIdx.x * 256 + threadIdx.x;
    if (e >= E) return;
    int s = src[e];
    int d = dst[e];
    int pos = atomicAdd(&cur[d >> BSH], 1);
    edata[pos] = make_int2(s, d);
}

// per-bucket in-degree histogram in LDS -> dinv = rsqrt(deg+1)
__global__ __launch_bounds__(256) void deg_dinv(
    const int2* __restrict__ edata, const int* __restrict__ off,
    float* __restrict__ dinv, int n)
{
    __shared__ int lcnt[BR];
    int b = blockIdx.x;
    int t = threadIdx.x;
    if (t < BR) lcnt[t] = 0;
    __syncthreads();
    int beg = off[b], end = off[b + 1];
    for (int e = beg + t; e < end; e += 256)
        atomicAdd(&lcnt[edata[e].y & (BR - 1)], 1);
    __syncthreads();
    if (t < BR) {
        int node = (b << BSH) + t;
        if (node < n) dinv[node] = rsqrtf((float)(lcnt[t] + 1));
    }
}

// ---------------------------------------------------------------------------
// MFMA GEMM: hw = f16(x) @ f16(W) + bhw, stored f16 [N][32].
// Epilogue inits f16 accumulator oacc = f16(gcn_b + dinv^2 * hw).
// LDS: only xs [64][256] f16 (32 KB), XOR-swizzled (slot = chunk ^ (row&7)).
// B-fragments come straight from global wlin (16 KB f16 image, L1-resident).
// Fragment maps (verified on HW, R4/R5 pass):
//   A[r][k]: lane=r+16*(k/8), elem=k%8;  B[k][c]: lane=c+16*(k/8), elem=k%8;
//   D[r][c]: lane=c+16*(r/4), reg=r%4.
// ---------------------------------------------------------------------------
__global__ __launch_bounds__(256) void gemm_mfma(
    const float* __restrict__ x,        // [N][256] f32
    const _Float16* __restrict__ wlin,  // [32*256] f16
    const float* __restrict__ bhw,      // [32]
    const float* __restrict__ dinv,     // [N]
    const float* __restrict__ gcn_b,    // [32]
    _Float16* __restrict__ hw2,         // [N][32] f16
    _Float16* __restrict__ oacc,        // [N][32] f16
    int n)
{
    __shared__ __align__(16) _Float16 xs[64 * 256];   // 32 KB

    int t = threadIdx.x;
    int row0 = blockIdx.x * 64;

    // stage x: half-wave h covers rows h, h+8, ...; lanes cover k (2 float4 each)
    {
        int hwid = t >> 5;
        int lk   = t & 31;
        const float4* xg = reinterpret_cast<const float4*>(x);
        float4 A[8], B[8];
#pragma unroll
        for (int g = 0; g < 8; ++g) {
            int r = g * 8 + hwid;
            int row = row0 + r;
            A[g] = make_float4(0.f, 0.f, 0.f, 0.f);
            B[g] = make_float4(0.f, 0.f, 0.f, 0.f);
            if (row < n) {
                const float4* p = xg + (size_t)row * 64 + lk * 2;
                A[g] = p[0];
                B[g] = p[1];
            }
        }
        char* xsb = reinterpret_cast<char*>(xs);
#pragma unroll
        for (int g = 0; g < 8; ++g) {
            int r = g * 8 + hwid;
            half8 h;
            h[0] = (_Float16)A[g].x; h[1] = (_Float16)A[g].y;
            h[2] = (_Float16)A[g].z; h[3] = (_Float16)A[g].w;
            h[4] = (_Float16)B[g].x; h[5] = (_Float16)B[g].y;
            h[6] = (_Float16)B[g].z; h[7] = (_Float16)B[g].w;
            int slot = lk ^ (r & 7);
            *reinterpret_cast<half8*>(xsb + r * 512 + slot * 16) = h;
        }
    }
    __syncthreads();

    int l = t & 63;
    int w = t >> 6;
    int lr   = l & 15;
    int acol = l >> 4;
    int arow = (w << 4) | lr;
    int axor = arow & 7;

    const char* xsb = reinterpret_cast<const char*>(xs);
    const _Float16* wb0 = wlin + lr * 256;
    const _Float16* wb1 = wlin + (lr + 16) * 256;

    f32x4 acc0 = {0.f, 0.f, 0.f, 0.f};
    f32x4 acc1 = {0.f, 0.f, 0.f, 0.f};
#pragma unroll
    for (int ks = 0; ks < 8; ++ks) {
        int ak = (ks << 2) | acol;
        half8 Af = *reinterpret_cast<const half8*>(xsb + arow * 512 + ((ak ^ axor) << 4));
        half8 B0 = *reinterpret_cast<const half8*>(wb0 + (ak << 3));
        half8 B1 = *reinterpret_cast<const half8*>(wb1 + (ak << 3));
        acc0 = __builtin_amdgcn_mfma_f32_16x16x32_f16(Af, B0, acc0, 0, 0, 0);
        acc1 = __builtin_amdgcn_mfma_f32_16x16x32_f16(Af, B1, acc1, 0, 0, 0);
    }

    int c0 = lr;
    int orow0 = row0 + (w << 4) + (acol << 2);
    float b0  = bhw[c0];
    float b1  = bhw[c0 + 16];
    float gb0 = gcn_b[c0];
    float gb1 = gcn_b[c0 + 16];
#pragma unroll
    for (int i = 0; i < 4; ++i) {
        int row = orow0 + i;
        if (row < n) {
            float h0 = acc0[i] + b0;
            float h1 = acc1[i] + b1;
            hw2[(size_t)row * OUT + c0]      = (_Float16)h0;
            hw2[(size_t)row * OUT + 16 + c0] = (_Float16)h1;
            float di = dinv[row];
            float d2 = di * di;
            oacc[(size_t)row * OUT + c0]      = (_Float16)(gb0 + d2 * h0);
            oacc[(size_t)row * OUT + 16 + c0] = (_Float16)(gb1 + d2 * h1);
        }
    }
}

// ---------------------------------------------------------------------------
// Phase B: one block per bucket. LDS f32 slice [128][32]; ds_add_f32 atomics
// (bank = feature -> conflict-free); final coalesced f32 write of out.
// ---------------------------------------------------------------------------
__global__ __launch_bounds__(256) void scatter_bucket(
    const int2* __restrict__ edata, const int* __restrict__ off,
    const float* __restrict__ dinv, const _Float16* __restrict__ hw2,
    const _Float16* __restrict__ oacc, float* __restrict__ out, int n)
{
    __shared__ float slice[BR * OUT];   // 16 KB

    int b = blockIdx.x;
    int t = threadIdx.x;
    for (int i = t; i < BR * OUT; i += 256) slice[i] = 0.f;
    __syncthreads();

    int beg = off[b], end = off[b + 1];
    int g = t >> 5;          // edge sub-slot 0..7
    int c = t & 31;          // feature

    auto process = [&](int e) {
        int2 rec = edata[e];
        int s = rec.x;
        int d = rec.y;
        float wgt = dinv[s] * dinv[d];
        float hv = (float)hw2[(size_t)s * OUT + c];
        atomicAdd(&slice[((d & (BR - 1)) << 5) + c], wgt * hv);
    };

    int e = beg + g;
    for (; e + 24 < end; e += 32) {     // 4-deep unroll for MLP
        process(e);
        process(e + 8);
        process(e + 16);
        process(e + 24);
    }
    for (; e < end; e += 8) process(e);
    __syncthreads();

    int base = b << BSH;
#pragma unroll
    for (int j = 0; j < BR * OUT / 256; ++j) {
        int idx = j * 256 + t;
        int node = base + (idx >> 5);
        int cc = idx & 31;
        if (node < n)
            out[(size_t)node * OUT + cc] = (float)oacc[(size_t)node * OUT + cc] + slice[idx];
    }
}

// ---------------------------------------------------------------------------
extern "C" void kernel_launch(void* const* d_in, const int* in_sizes, int n_in,
                              void* d_out, int out_size, void* d_ws, size_t ws_size,
                              hipStream_t stream)
{
    const float* x      = (const float*)d_in[0];
    const int*   eidx   = (const int*)d_in[1];
    const float* fc1_w  = (const float*)d_in[2];
    const float* fc1_b  = (const float*)d_in[3];
    const float* gcn_w  = (const float*)d_in[4];
    const float* gcn_b  = (const float*)d_in[5];
    float* out = (float*)d_out;

    int n = in_sizes[0] / IN_FEAT;
    int E = in_sizes[1] / 2;
    const int* src = eidx;
    const int* dst = eidx + E;
    int NB = (n + BR - 1) >> BSH;

    auto align4 = [](size_t v) { return (v + 3) & ~(size_t)3; };
    float* ws = (float*)d_ws;
    size_t o = 0;
    _Float16* wlin = (_Float16*)(ws + o); o = align4(o + 4096);        // 32*256 f16 = 16 KB = 4096 floats
    float*    bhw  = ws + o;              o = align4(o + OUT);
    float*    dinv = ws + o;              o = align4(o + n);
    int*      bcnt = (int*)(ws + o);      o = align4(o + NB);
    int*      off  = (int*)(ws + o);      o = align4(o + NB + 1);
    int*      cur  = (int*)(ws + o);      o = align4(o + NB);
    int2*     edata = (int2*)(ws + o);    o = align4(o + (size_t)2 * E);
    _Float16* hw2  = (_Float16*)(ws + o); o = align4(o + (size_t)n * OUT / 2);
    _Float16* oacc = (_Float16*)(ws + o); o = align4(o + (size_t)n * OUT / 2);
    (void)ws_size;

    dim3 blk(256);
    prep_W<<<dim3((IN_FEAT * OUT) / 256), blk, 0, stream>>>(fc1_w, fc1_b, gcn_w, wlin, bhw);
    zero_i32<<<dim3((NB + 255) / 256), blk, 0, stream>>>(bcnt, NB);
    bucket_count<<<dim3((E + 255) / 256), blk, 0, stream>>>(dst, bcnt, E);
    bucket_scan<<<dim3(1), blk, 0, stream>>>(bcnt, off, cur, NB);
    bin_edges<<<dim3((E + 255) / 256), blk, 0, stream>>>(src, dst, cur, edata, E);
    deg_dinv<<<dim3(NB), blk, 0, stream>>>(edata, off, dinv, n);
    gemm_mfma<<<dim3((n + 63) / 64), blk, 0, stream>>>(
        x, wlin, bhw, dinv, gcn_b, hw2, oacc, n);
    scatter_bucket<<<dim3(NB), blk, 0, stream>>>(
        edata, off, dinv, hw2, oacc, out, n);
}

// Round 8
// 347.542 us; speedup vs baseline: 3.7198x; 3.7198x over previous
//
#include <hip/hip_runtime.h>
#include <hip/hip_fp16.h>

constexpr int IN_FEAT = 256;
constexpr int HID     = 64;
constexpr int OUT     = 32;

typedef _Float16 half8 __attribute__((ext_vector_type(8)));
typedef float    f32x4 __attribute__((ext_vector_type(4)));

// ---------------------------------------------------------------------------
// Fold the two linears: wlin[c][k] = sum_h fc1_w[h][k]*gcn_w[h][c]  (f16),
// bhw = fc1_b @ gcn_w. wlin is [32][256] f16 linear = 16 KB, L1/L2-resident.
// ---------------------------------------------------------------------------
__global__ __launch_bounds__(256) void prep_W(
    const float* __restrict__ fc1_w,   // [HID][IN_FEAT]
    const float* __restrict__ fc1_b,   // [HID]
    const float* __restrict__ gcn_w,   // [HID][OUT]
    _Float16* __restrict__ wlin,       // [32*256] f16
    float* __restrict__ bhw)           // [OUT]
{
    int idx = blockIdx.x * 256 + threadIdx.x;   // 0 .. 8191
    int k = idx >> 5;
    int c = idx & 31;
    float acc = 0.f;
#pragma unroll
    for (int h = 0; h < HID; ++h)
        acc += fc1_w[h * IN_FEAT + k] * gcn_w[h * OUT + c];
    wlin[c * 256 + k] = (_Float16)acc;

    if (idx < OUT) {
        float b = 0.f;
#pragma unroll
        for (int h = 0; h < HID; ++h)
            b += fc1_b[h] * gcn_w[h * OUT + idx];
        bhw[idx] = b;
    }
}

// ---------------------------------------------------------------------------
// Degree: zero, count in-edges (fire-and-forget int atomics, ~17 contenders
// per address -> benign per R7's contention model), dinv = rsqrt(deg+1).
// ---------------------------------------------------------------------------
__global__ __launch_bounds__(256) void zero_cnt(int* __restrict__ cnt, int n)
{
    int i = blockIdx.x * 256 + threadIdx.x;
    if (i < n) cnt[i] = 0;
}

__global__ __launch_bounds__(256) void count_deg(
    const int* __restrict__ dst, int* __restrict__ cnt, int E)
{
    int e = blockIdx.x * 256 + threadIdx.x;
    if (e < E) atomicAdd(&cnt[dst[e]], 1);
}

__global__ __launch_bounds__(256) void make_dinv(
    const int* __restrict__ cnt, float* __restrict__ dinv, int n)
{
    int i = blockIdx.x * 256 + threadIdx.x;
    if (i < n) dinv[i] = rsqrtf((float)(cnt[i] + 1));
}

// ---------------------------------------------------------------------------
// MFMA GEMM: hw = f16(x) @ f16(W) + bhw, stored f16 [N][32].
// Epilogue inits f16 accumulator oacc = f16(gcn_b + dinv^2 * hw).
// LDS: only xs [64][256] f16 (32 KB -> 5 blocks/CU), XOR-swizzled
// (slot = chunk ^ (row&7)). B-fragments straight from global wlin
// (16 KB f16 image, L1-resident).   [R7-validated version]
// Fragment maps (verified on HW, R4/R5/R7 pass):
//   A[r][k]: lane=r+16*(k/8), elem=k%8;  B[k][c]: lane=c+16*(k/8), elem=k%8;
//   D[r][c]: lane=c+16*(r/4), reg=r%4.
// ---------------------------------------------------------------------------
__global__ __launch_bounds__(256) void gemm_mfma(
    const float* __restrict__ x,        // [N][256] f32
    const _Float16* __restrict__ wlin,  // [32*256] f16
    const float* __restrict__ bhw,      // [32]
    const float* __restrict__ dinv,     // [N]
    const float* __restrict__ gcn_b,    // [32]
    _Float16* __restrict__ hw2,         // [N][32] f16
    _Float16* __restrict__ oacc,        // [N][32] f16
    int n)
{
    __shared__ __align__(16) _Float16 xs[64 * 256];   // 32 KB

    int t = threadIdx.x;
    int row0 = blockIdx.x * 64;

    // stage x: half-wave h covers rows h, h+8, ...; lanes cover k (2 float4 each)
    {
        int hwid = t >> 5;
        int lk   = t & 31;
        const float4* xg = reinterpret_cast<const float4*>(x);
        float4 A[8], B[8];
#pragma unroll
        for (int g = 0; g < 8; ++g) {
            int r = g * 8 + hwid;
            int row = row0 + r;
            A[g] = make_float4(0.f, 0.f, 0.f, 0.f);
            B[g] = make_float4(0.f, 0.f, 0.f, 0.f);
            if (row < n) {
                const float4* p = xg + (size_t)row * 64 + lk * 2;
                A[g] = p[0];
                B[g] = p[1];
            }
        }
        char* xsb = reinterpret_cast<char*>(xs);
#pragma unroll
        for (int g = 0; g < 8; ++g) {
            int r = g * 8 + hwid;
            half8 h;
            h[0] = (_Float16)A[g].x; h[1] = (_Float16)A[g].y;
            h[2] = (_Float16)A[g].z; h[3] = (_Float16)A[g].w;
            h[4] = (_Float16)B[g].x; h[5] = (_Float16)B[g].y;
            h[6] = (_Float16)B[g].z; h[7] = (_Float16)B[g].w;
            int slot = lk ^ (r & 7);
            *reinterpret_cast<half8*>(xsb + r * 512 + slot * 16) = h;
        }
    }
    __syncthreads();

    int l = t & 63;
    int w = t >> 6;
    int lr   = l & 15;
    int acol = l >> 4;
    int arow = (w << 4) | lr;
    int axor = arow & 7;

    const char* xsb = reinterpret_cast<const char*>(xs);
    const _Float16* wb0 = wlin + lr * 256;
    const _Float16* wb1 = wlin + (lr + 16) * 256;

    f32x4 acc0 = {0.f, 0.f, 0.f, 0.f};
    f32x4 acc1 = {0.f, 0.f, 0.f, 0.f};
#pragma unroll
    for (int ks = 0; ks < 8; ++ks) {
        int ak = (ks << 2) | acol;
        half8 Af = *reinterpret_cast<const half8*>(xsb + arow * 512 + ((ak ^ axor) << 4));
        half8 B0 = *reinterpret_cast<const half8*>(wb0 + (ak << 3));
        half8 B1 = *reinterpret_cast<const half8*>(wb1 + (ak << 3));
        acc0 = __builtin_amdgcn_mfma_f32_16x16x32_f16(Af, B0, acc0, 0, 0, 0);
        acc1 = __builtin_amdgcn_mfma_f32_16x16x32_f16(Af, B1, acc1, 0, 0, 0);
    }

    int c0 = lr;
    int orow0 = row0 + (w << 4) + (acol << 2);
    float b0  = bhw[c0];
    float b1  = bhw[c0 + 16];
    float gb0 = gcn_b[c0];
    float gb1 = gcn_b[c0 + 16];
#pragma unroll
    for (int i = 0; i < 4; ++i) {
        int row = orow0 + i;
        if (row < n) {
            float h0 = acc0[i] + b0;
            float h1 = acc1[i] + b1;
            hw2[(size_t)row * OUT + c0]      = (_Float16)h0;
            hw2[(size_t)row * OUT + 16 + c0] = (_Float16)h1;
            float di = dinv[row];
            float d2 = di * di;
            oacc[(size_t)row * OUT + c0]      = (_Float16)(gb0 + d2 * h0);
            oacc[(size_t)row * OUT + 16 + c0] = (_Float16)(gb1 + d2 * h1);
        }
    }
}

// ---------------------------------------------------------------------------
// Edge scatter with packed-f16 atomics: 16 lanes per edge, lane = half2 pair.
//   oacc[d][2c:2c+2] += dinv[s]*dinv[d] * hw2[s][2c:2c+2]
// unsafeAtomicAdd -> global_atomic_pk_add_f16; one 64B line per edge.
// ---------------------------------------------------------------------------
__global__ __launch_bounds__(256) void scatter_f16(
    const int* __restrict__ src, const int* __restrict__ dst,
    const float* __restrict__ dinv,
    const __half2* __restrict__ hw2,     // [N][16] half2
    __half2* __restrict__ oacc,          // [N][16] half2
    int E)
{
    int t = blockIdx.x * 256 + threadIdx.x;
    int e = t >> 4;
    int c = t & 15;
    if (e >= E) return;
    int s = src[e];
    int d = dst[e];
    float w = dinv[s] * dinv[d];
    __half2 hv = hw2[(size_t)s * 16 + c];
    __half2 val = __floats2half2_rn(w * __low2float(hv), w * __high2float(hv));
    unsafeAtomicAdd(&oacc[(size_t)d * 16 + c], val);
}

// ---------------------------------------------------------------------------
// Final convert f16 accumulator -> f32 output.
// ---------------------------------------------------------------------------
__global__ __launch_bounds__(256) void convert_out(
    const __half2* __restrict__ oacc, float2* __restrict__ out, int n16)
{
    int i = blockIdx.x * 256 + threadIdx.x;
    if (i >= n16) return;
    __half2 h = oacc[i];
    out[i] = make_float2(__low2float(h), __high2float(h));
}

// ---------------------------------------------------------------------------
extern "C" void kernel_launch(void* const* d_in, const int* in_sizes, int n_in,
                              void* d_out, int out_size, void* d_ws, size_t ws_size,
                              hipStream_t stream)
{
    const float* x      = (const float*)d_in[0];
    const int*   eidx   = (const int*)d_in[1];
    const float* fc1_w  = (const float*)d_in[2];
    const float* fc1_b  = (const float*)d_in[3];
    const float* gcn_w  = (const float*)d_in[4];
    const float* gcn_b  = (const float*)d_in[5];
    float* out = (float*)d_out;

    int n = in_sizes[0] / IN_FEAT;
    int E = in_sizes[1] / 2;
    const int* src = eidx;
    const int* dst = eidx + E;

    auto align4 = [](size_t v) { return (v + 3) & ~(size_t)3; };
    float* ws = (float*)d_ws;
    size_t o = 0;
    _Float16* wlin = (_Float16*)(ws + o); o = align4(o + 4096);   // 8192 f16 = 16 KB = 4096 floats
    float*    bhw  = ws + o;              o = align4(o + OUT);
    float*    dinv = ws + o;              o = align4(o + n);
    int*      cnt  = (int*)(ws + o);      o = align4(o + n);
    _Float16* hw2  = (_Float16*)(ws + o); o = align4(o + (size_t)n * OUT / 2);
    _Float16* oacc = (_Float16*)(ws + o); o = align4(o + (size_t)n * OUT / 2);
    (void)ws_size;

    dim3 blk(256);
    prep_W<<<dim3((IN_FEAT * OUT) / 256), blk, 0, stream>>>(fc1_w, fc1_b, gcn_w, wlin, bhw);
    zero_cnt<<<dim3((n + 255) / 256), blk, 0, stream>>>(cnt, n);
    count_deg<<<dim3((E + 255) / 256), blk, 0, stream>>>(dst, cnt, E);
    make_dinv<<<dim3((n + 255) / 256), blk, 0, stream>>>(cnt, dinv, n);
    gemm_mfma<<<dim3((n + 63) / 64), blk, 0, stream>>>(
        x, wlin, bhw, dinv, gcn_b, hw2, oacc, n);
    long long sthreads = (long long)E * 16;
    scatter_f16<<<dim3((int)((sthreads + 255) / 256)), blk, 0, stream>>>(
        src, dst, dinv, (const __half2*)hw2, (__half2*)oacc, E);
    int n16 = n * OUT / 2;
    convert_out<<<dim3((n16 + 255) / 256), blk, 0, stream>>>(
        (const __half2*)oacc, (float2*)out, n16);
}

// Round 9
// 344.133 us; speedup vs baseline: 3.7566x; 1.0099x over previous
//
#include <hip/hip_runtime.h>
#include <hip/hip_fp16.h>

constexpr int IN_FEAT = 256;
constexpr int HID     = 64;
constexpr int OUT     = 32;

typedef _Float16 half8 __attribute__((ext_vector_type(8)));
typedef float    f32x4 __attribute__((ext_vector_type(4)));

// ---------------------------------------------------------------------------
// Fold the two linears: wlin[c][k] = sum_h fc1_w[h][k]*gcn_w[h][c]  (f16),
// bhw = fc1_b @ gcn_w. wlin is [32][256] f16 linear = 16 KB, L1/L2-resident.
// ---------------------------------------------------------------------------
__global__ __launch_bounds__(256) void prep_W(
    const float* __restrict__ fc1_w,   // [HID][IN_FEAT]
    const float* __restrict__ fc1_b,   // [HID]
    const float* __restrict__ gcn_w,   // [HID][OUT]
    _Float16* __restrict__ wlin,       // [32*256] f16
    float* __restrict__ bhw)           // [OUT]
{
    int idx = blockIdx.x * 256 + threadIdx.x;   // 0 .. 8191
    int k = idx >> 5;
    int c = idx & 31;
    float acc = 0.f;
#pragma unroll
    for (int h = 0; h < HID; ++h)
        acc += fc1_w[h * IN_FEAT + k] * gcn_w[h * OUT + c];
    wlin[c * 256 + k] = (_Float16)acc;

    if (idx < OUT) {
        float b = 0.f;
#pragma unroll
        for (int h = 0; h < HID; ++h)
            b += fc1_b[h] * gcn_w[h * OUT + idx];
        bhw[idx] = b;
    }
}

// ---------------------------------------------------------------------------
// Degree counting with LINE-SPREAD counters: cnt[node*16] so each counter
// owns its own 64B line. R7 measured atomic cost ∝ per-line serialization
// depth (782 hot lines -> 377us); this drops depth 256 -> ~16, the regime
// scatter_f16 already proves runs at full atomic throughput.
// ---------------------------------------------------------------------------
__global__ __launch_bounds__(256) void zero_cnt(int* __restrict__ cnt, int n16)
{
    int i = blockIdx.x * 256 + threadIdx.x;
    if (i < n16) cnt[i] = 0;
}

__global__ __launch_bounds__(256) void count_deg(
    const int* __restrict__ dst, int* __restrict__ cnt, int E)
{
    int e = blockIdx.x * 256 + threadIdx.x;
    if (e < E) atomicAdd(&cnt[dst[e] << 4], 1);
}

__global__ __launch_bounds__(256) void make_dinv(
    const int* __restrict__ cnt, float* __restrict__ dinv, int n)
{
    int i = blockIdx.x * 256 + threadIdx.x;
    if (i < n) dinv[i] = rsqrtf((float)(cnt[i << 4] + 1));
}

// ---------------------------------------------------------------------------
// MFMA GEMM: hw = f16(x) @ f16(W) + bhw, stored f16 [N][32].
// Epilogue inits f16 accumulator oacc = f16(gcn_b + dinv^2 * hw).
// LDS: xs [64][256] f16 (32 KB), XOR-swizzled (slot = chunk ^ (row&7)).
// B-fragments straight from global wlin (16 KB f16 image, L1-resident).
// BYTE-IDENTICAL to R8 (single-variable discipline: only cnt layout changed).
// Fragment maps (verified on HW, R4/R5/R7/R8 pass):
//   A[r][k]: lane=r+16*(k/8), elem=k%8;  B[k][c]: lane=c+16*(k/8), elem=k%8;
//   D[r][c]: lane=c+16*(r/4), reg=r%4.
// ---------------------------------------------------------------------------
__global__ __launch_bounds__(256) void gemm_mfma(
    const float* __restrict__ x,        // [N][256] f32
    const _Float16* __restrict__ wlin,  // [32*256] f16
    const float* __restrict__ bhw,      // [32]
    const float* __restrict__ dinv,     // [N]
    const float* __restrict__ gcn_b,    // [32]
    _Float16* __restrict__ hw2,         // [N][32] f16
    _Float16* __restrict__ oacc,        // [N][32] f16
    int n)
{
    __shared__ __align__(16) _Float16 xs[64 * 256];   // 32 KB

    int t = threadIdx.x;
    int row0 = blockIdx.x * 64;

    // stage x: half-wave h covers rows h, h+8, ...; lanes cover k (2 float4 each)
    {
        int hwid = t >> 5;
        int lk   = t & 31;
        const float4* xg = reinterpret_cast<const float4*>(x);
        float4 A[8], B[8];
#pragma unroll
        for (int g = 0; g < 8; ++g) {
            int r = g * 8 + hwid;
            int row = row0 + r;
            A[g] = make_float4(0.f, 0.f, 0.f, 0.f);
            B[g] = make_float4(0.f, 0.f, 0.f, 0.f);
            if (row < n) {
                const float4* p = xg + (size_t)row * 64 + lk * 2;
                A[g] = p[0];
                B[g] = p[1];
            }
        }
        char* xsb = reinterpret_cast<char*>(xs);
#pragma unroll
        for (int g = 0; g < 8; ++g) {
            int r = g * 8 + hwid;
            half8 h;
            h[0] = (_Float16)A[g].x; h[1] = (_Float16)A[g].y;
            h[2] = (_Float16)A[g].z; h[3] = (_Float16)A[g].w;
            h[4] = (_Float16)B[g].x; h[5] = (_Float16)B[g].y;
            h[6] = (_Float16)B[g].z; h[7] = (_Float16)B[g].w;
            int slot = lk ^ (r & 7);
            *reinterpret_cast<half8*>(xsb + r * 512 + slot * 16) = h;
        }
    }
    __syncthreads();

    int l = t & 63;
    int w = t >> 6;
    int lr   = l & 15;
    int acol = l >> 4;
    int arow = (w << 4) | lr;
    int axor = arow & 7;

    const char* xsb = reinterpret_cast<const char*>(xs);
    const _Float16* wb0 = wlin + lr * 256;
    const _Float16* wb1 = wlin + (lr + 16) * 256;

    f32x4 acc0 = {0.f, 0.f, 0.f, 0.f};
    f32x4 acc1 = {0.f, 0.f, 0.f, 0.f};
#pragma unroll
    for (int ks = 0; ks < 8; ++ks) {
        int ak = (ks << 2) | acol;
        half8 Af = *reinterpret_cast<const half8*>(xsb + arow * 512 + ((ak ^ axor) << 4));
        half8 B0 = *reinterpret_cast<const half8*>(wb0 + (ak << 3));
        half8 B1 = *reinterpret_cast<const half8*>(wb1 + (ak << 3));
        acc0 = __builtin_amdgcn_mfma_f32_16x16x32_f16(Af, B0, acc0, 0, 0, 0);
        acc1 = __builtin_amdgcn_mfma_f32_16x16x32_f16(Af, B1, acc1, 0, 0, 0);
    }

    int c0 = lr;
    int orow0 = row0 + (w << 4) + (acol << 2);
    float b0  = bhw[c0];
    float b1  = bhw[c0 + 16];
    float gb0 = gcn_b[c0];
    float gb1 = gcn_b[c0 + 16];
#pragma unroll
    for (int i = 0; i < 4; ++i) {
        int row = orow0 + i;
        if (row < n) {
            float h0 = acc0[i] + b0;
            float h1 = acc1[i] + b1;
            hw2[(size_t)row * OUT + c0]      = (_Float16)h0;
            hw2[(size_t)row * OUT + 16 + c0] = (_Float16)h1;
            float di = dinv[row];
            float d2 = di * di;
            oacc[(size_t)row * OUT + c0]      = (_Float16)(gb0 + d2 * h0);
            oacc[(size_t)row * OUT + 16 + c0] = (_Float16)(gb1 + d2 * h1);
        }
    }
}

// ---------------------------------------------------------------------------
// Edge scatter with packed-f16 atomics: 16 lanes per edge, lane = half2 pair.
//   oacc[d][2c:2c+2] += dinv[s]*dinv[d] * hw2[s][2c:2c+2]
// unsafeAtomicAdd -> global_atomic_pk_add_f16; one 64B line per edge.
// ---------------------------------------------------------------------------
__global__ __launch_bounds__(256) void scatter_f16(
    const int* __restrict__ src, const int* __restrict__ dst,
    const float* __restrict__ dinv,
    const __half2* __restrict__ hw2,     // [N][16] half2
    __half2* __restrict__ oacc,          // [N][16] half2
    int E)
{
    int t = blockIdx.x * 256 + threadIdx.x;
    int e = t >> 4;
    int c = t & 15;
    if (e >= E) return;
    int s = src[e];
    int d = dst[e];
    float w = dinv[s] * dinv[d];
    __half2 hv = hw2[(size_t)s * 16 + c];
    __half2 val = __floats2half2_rn(w * __low2float(hv), w * __high2float(hv));
    unsafeAtomicAdd(&oacc[(size_t)d * 16 + c], val);
}

// ---------------------------------------------------------------------------
// Final convert f16 accumulator -> f32 output.
// ---------------------------------------------------------------------------
__global__ __launch_bounds__(256) void convert_out(
    const __half2* __restrict__ oacc, float2* __restrict__ out, int n16)
{
    int i = blockIdx.x * 256 + threadIdx.x;
    if (i >= n16) return;
    __half2 h = oacc[i];
    out[i] = make_float2(__low2float(h), __high2float(h));
}

// ---------------------------------------------------------------------------
extern "C" void kernel_launch(void* const* d_in, const int* in_sizes, int n_in,
                              void* d_out, int out_size, void* d_ws, size_t ws_size,
                              hipStream_t stream)
{
    const float* x      = (const float*)d_in[0];
    const int*   eidx   = (const int*)d_in[1];
    const float* fc1_w  = (const float*)d_in[2];
    const float* fc1_b  = (const float*)d_in[3];
    const float* gcn_w  = (const float*)d_in[4];
    const float* gcn_b  = (const float*)d_in[5];
    float* out = (float*)d_out;

    int n = in_sizes[0] / IN_FEAT;
    int E = in_sizes[1] / 2;
    const int* src = eidx;
    const int* dst = eidx + E;

    auto align4 = [](size_t v) { return (v + 3) & ~(size_t)3; };
    float* ws = (float*)d_ws;
    size_t o = 0;
    _Float16* wlin = (_Float16*)(ws + o); o = align4(o + 4096);   // 8192 f16 = 16 KB = 4096 floats
    float*    bhw  = ws + o;              o = align4(o + OUT);
    float*    dinv = ws + o;              o = align4(o + n);
    int*      cnt  = (int*)(ws + o);      o = align4(o + (size_t)n * 16);  // line-spread counters
    _Float16* hw2  = (_Float16*)(ws + o); o = align4(o + (size_t)n * OUT / 2);
    _Float16* oacc = (_Float16*)(ws + o); o = align4(o + (size_t)n * OUT / 2);
    (void)ws_size;

    int n16cnt = n * 16;
    dim3 blk(256);
    prep_W<<<dim3((IN_FEAT * OUT) / 256), blk, 0, stream>>>(fc1_w, fc1_b, gcn_w, wlin, bhw);
    zero_cnt<<<dim3((n16cnt + 255) / 256), blk, 0, stream>>>(cnt, n16cnt);
    count_deg<<<dim3((E + 255) / 256), blk, 0, stream>>>(dst, cnt, E);
    make_dinv<<<dim3((n + 255) / 256), blk, 0, stream>>>(cnt, dinv, n);
    gemm_mfma<<<dim3((n + 63) / 64), blk, 0, stream>>>(
        x, wlin, bhw, dinv, gcn_b, hw2, oacc, n);
    long long sthreads = (long long)E * 16;
    scatter_f16<<<dim3((int)((sthreads + 255) / 256)), blk, 0, stream>>>(
        src, dst, dinv, (const __half2*)hw2, (__half2*)oacc, E);
    int n16 = n * OUT / 2;
    convert_out<<<dim3((n16 + 255) / 256), blk, 0, stream>>>(
        (const __half2*)oacc, (float2*)out, n16);
}